// Round 11
// baseline (306.095 us; speedup 1.0000x reference)
//
#include <hip/hip_runtime.h>
#include <hip/hip_bf16.h>
#include <stdint.h>

// ---------------------------------------------------------------------------
// ChebConv with attention + per-(t,k) dropout, MI355X bf16 MFMA implementation
// out[b,t,u,o] = relu( sum_k M[t,k] @ (x[b,t] @ Theta[k]) )
// M[t,k,u,v] = mask(t,k,u,v) ? cheb[k,u,v]*Att[u,v]/0.4 : 0
// mask = threefry2x32 partitionable, key(42), bits = x0^x1   (verified R0)
// B=32 T=12 V=1000(pad 1024) F=O=64 K=3
//
// R11: A (M) bypasses LDS entirely. build_m writes M in MFMA FRAGMENT order:
//   Mf element index = (((tk*64 + u16)*16 + vc)*2 + ks)*512 + lane*8 + j
//   where u = u16*16 + (lane&15), v = vc*64 + ks*32 + (lane>>4)*8 + j.
// A-fragment load in cheb_main = ONE coalesced global_load_dwordx4 per frag
// (base + lane*16B), VGPR-direct. LDS stages only B (16KB/chunk, shared
// across the 3 k) -> LDS instr per chunk 224 -> 80. R8-R10 were pinned at
// MfmaUtil ~33% by LDS instruction throughput (A = 3/4 of traffic).
// XCD-bijective grid swizzle (ut = bid&7) keeps each XCD's A slab L2-resident
// (16 nt-blocks of one (ut,t) share one XCD). xt reuse served by L3 (50MB).
// ws: Mf bf16 [36 * 1024 * 1024] fragment-ordered | xt bf16 [12][2048][1024]
// ---------------------------------------------------------------------------

typedef __attribute__((ext_vector_type(8))) short short8;
typedef __attribute__((ext_vector_type(4))) float f32x4;

__device__ __forceinline__ ushort f2bf(float f) {
  __hip_bfloat16 h = __float2bfloat16(f);
  return *reinterpret_cast<ushort*>(&h);
}

__device__ __forceinline__ void threefry2x32(uint32_t c0, uint32_t c1,
                                             uint32_t& o0, uint32_t& o1) {
  const uint32_t ks0 = 0u;
  const uint32_t ks1 = 42u;
  const uint32_t ks2 = ks0 ^ ks1 ^ 0x1BD11BDAu;
  uint32_t x0 = c0 + ks0;
  uint32_t x1 = c1 + ks1;
#define TFR(r) { x0 += x1; x1 = (x1 << (r)) | (x1 >> (32 - (r))); x1 ^= x0; }
  TFR(13) TFR(15) TFR(26) TFR(6)
  x0 += ks1; x1 += ks2 + 1u;
  TFR(17) TFR(29) TFR(16) TFR(24)
  x0 += ks2; x1 += ks0 + 2u;
  TFR(13) TFR(15) TFR(26) TFR(6)
  x0 += ks0; x1 += ks1 + 3u;
  TFR(17) TFR(29) TFR(16) TFR(24)
  x0 += ks1; x1 += ks2 + 4u;
  TFR(13) TFR(15) TFR(26) TFR(6)
  x0 += ks2; x1 += ks0 + 5u;
#undef TFR
  o0 = x0; o1 = x1;
}

// ---------------------------------------------------------------------------
// Kernel 1: build masked M (bf16) in MFMA-fragment order.
// Thread handles output offset idx (coalesced write); decodes (tk,u,v):
//   j=idx&7, lane=(idx>>3)&63, ks=(idx>>9)&1, c=(idx>>10)&15,
//   u16=(idx>>14)&63, tk=idx>>20;  u=u16*16+(lane&15),
//   v=c*64+ks*32+(lane>>4)*8+j.
// ---------------------------------------------------------------------------
__global__ void build_m(const float* __restrict__ Att,
                        const float* __restrict__ cheb,
                        ushort* __restrict__ Mf) {
  const uint32_t idx = blockIdx.x * 256u + threadIdx.x;
  const uint32_t j = idx & 7u;
  const uint32_t lane = (idx >> 3) & 63u;
  const uint32_t ks = (idx >> 9) & 1u;
  const uint32_t c = (idx >> 10) & 15u;
  const uint32_t u16 = (idx >> 14) & 63u;
  const uint32_t tk = idx >> 20;
  const uint32_t up = u16 * 16u + (lane & 15u);
  const uint32_t vp = c * 64u + ks * 32u + (lane >> 4) * 8u + j;
  float val = 0.f;
  if ((vp < 1000u) & (up < 1000u)) {
    const uint32_t flat = (tk * 1000u + up) * 1000u + vp;
    uint32_t o0, o1;
    threefry2x32(0u, flat, o0, o1);
    const uint32_t bits = o0 ^ o1;
    const float u = __uint_as_float((bits >> 9) | 0x3f800000u) - 1.0f;
    if (u < 0.4f) {
      val = cheb[(tk % 3u) * 1000000u + up * 1000u + vp] *
            Att[up * 1000u + vp] * 2.5f;
    }
  }
  Mf[idx] = f2bf(val);
}

// ---------------------------------------------------------------------------
// Kernel 2: xt[t][n=b*64+f][v(1024 pad)] bf16  <-  x[b][t][v][f] f32
// ---------------------------------------------------------------------------
__global__ void transpose_x(const float* __restrict__ x,
                            ushort* __restrict__ xt) {
  __shared__ float lt[64][65];
  const int vc = blockIdx.x, t = blockIdx.y, b = blockIdx.z;
  const int tid = threadIdx.x;
  const int v0 = vc * 64;
#pragma unroll
  for (int i = 0; i < 4; ++i) {
    const int c = i * 256 + tid;
    const int vi = c >> 4, f4 = c & 15;
    float4 q = make_float4(0.f, 0.f, 0.f, 0.f);
    if (v0 + vi < 1000)
      q = *(const float4*)(x + ((((size_t)b * 12 + t) * 1000 + v0 + vi) << 6) + f4 * 4);
    lt[f4 * 4 + 0][vi] = q.x;
    lt[f4 * 4 + 1][vi] = q.y;
    lt[f4 * 4 + 2][vi] = q.z;
    lt[f4 * 4 + 3][vi] = q.w;
  }
  __syncthreads();
  const int f = tid >> 2, g = tid & 3;
  alignas(16) ushort tmp[16];
#pragma unroll
  for (int j = 0; j < 16; ++j) tmp[j] = f2bf(lt[f][g * 16 + j]);
  const size_t base = ((size_t)(t * 2048 + b * 64 + f)) << 10;
  *(uint4*)(xt + base + v0 + g * 16)     = *(const uint4*)&tmp[0];
  *(uint4*)(xt + base + v0 + g * 16 + 8) = *(const uint4*)&tmp[8];
}

// ---------------------------------------------------------------------------
// Kernel 3: main fused GEMM.  512 thr (8 waves), tile 128u x 128n per t,
// wave tile 32u x 64n.  Per 64-chunk: A-frags = 12 coalesced global loads
// (fragment-ordered Mf, VGPR-direct); B staged in LDS (16KB dbuf, XOR
// swizzle, shared across 3 k).  48 MFMA -> pacc[3] (AGPR).  Stage 2:
// pacc[k] -> sP(bf16) -> oacc += P @ ThetaT[k].  Relu + f32 store.
// Grid: 1D 1536, XCD-bijective: nt=(bid>>3)&15, ut=bid&7, t=bid>>7
// (all blocks on XCD x share ut=x -> A slab L2-resident per XCD).
// ---------------------------------------------------------------------------
#define LDT 72

#define MFMA(a, b, c) __builtin_amdgcn_mfma_f32_16x16x32_bf16((a), (b), (c), 0, 0, 0)

// B-only burst: A from registers afr[k][mi][ks], B from LDS buffer BP.
#define BURST(BP)                                                             \
  do {                                                                        \
    const ushort* sBc = (BP);                                                 \
    _Pragma("unroll")                                                         \
    for (int ks = 0; ks < 2; ++ks) {                                          \
      short8 bv[4];                                                           \
      _Pragma("unroll")                                                       \
      for (int ni = 0; ni < 4; ++ni) {                                        \
        const int row = wn * 64 + ni * 16 + l15;                              \
        bv[ni] = *(const short8*)&sBc[row * 64 + (((ks * 4 + quad) ^ rsw) * 8)]; \
      }                                                                       \
      _Pragma("unroll")                                                       \
      for (int k = 0; k < 3; ++k)                                             \
        _Pragma("unroll")                                                     \
        for (int mi = 0; mi < 2; ++mi)                                        \
          _Pragma("unroll")                                                   \
          for (int ni = 0; ni < 4; ++ni)                                      \
            pacc[k][mi][ni] = MFMA(afr[k][mi][ks], bv[ni], pacc[k][mi][ni]);  \
    }                                                                         \
  } while (0)

// load the 12 A fragments for chunk VC into afr (coalesced, VGPR-direct)
#define LOAD_A(VC)                                                            \
  do {                                                                        \
    _Pragma("unroll")                                                         \
    for (int k = 0; k < 3; ++k)                                               \
      _Pragma("unroll")                                                       \
      for (int mi = 0; mi < 2; ++mi)                                          \
        _Pragma("unroll")                                                     \
        for (int ks = 0; ks < 2; ++ks)                                        \
          afr[k][mi][ks] = *(const short8*)(Mf + fb[k][mi] +                  \
                             (size_t)(VC) * 1024 + ks * 512 + lane * 8);      \
  } while (0)

// barrier WITHOUT vmcnt drain (B ds_write visibility only)
#define SOFT_BARRIER()                                                        \
  do {                                                                        \
    asm volatile("s_waitcnt lgkmcnt(0)" ::: "memory");                        \
    __builtin_amdgcn_s_barrier();                                             \
    __builtin_amdgcn_sched_barrier(0);                                        \
  } while (0)

__global__ __launch_bounds__(512, 1)
void cheb_main(const ushort* __restrict__ Mf, const ushort* __restrict__ xt,
               const float* __restrict__ Theta, float* __restrict__ out) {
  // LDS: buf0 [0,8192) ushorts, buf1 [8192,16384); stage-2 overlays:
  // sP = w*2304 (max 18432), sTh at 18432..23040.  46080 B total.
  __shared__ __align__(16) ushort smem[23040];
  const int tid = threadIdx.x;
  const int lane = tid & 63;
  const int w = tid >> 6;              // wave 0..7
  const int wu = w >> 1, wn = w & 1;   // wave tile: u = wu*32, n = wn*64
  const int quad = lane >> 4, l15 = lane & 15;
  const int bid = blockIdx.x;          // XCD-bijective decode
  const int nt = (bid >> 3) & 15;
  const int ut = bid & 7;
  const int t  = bid >> 7;
  const int u0 = ut * 128, n0 = nt * 128;

  ushort* buf0 = smem;
  ushort* buf1 = smem + 8192;
  ushort* sP  = smem + w * (32 * LDT);
  ushort* sTh = smem + 18432;

  const int srow = lane >> 3;            // B staging row-in-group
  const int gchunk = (lane & 7) ^ srow;  // pre-swizzled source chunk
  const int rsw = l15 & 7;               // read-side swizzle key

  const size_t xrow0 = (size_t)(t * 2048 + n0);
  const int rr0 = 8 * (w * 2 + 0) + srow;
  const int rr1 = 8 * (w * 2 + 1) + srow;
  const size_t gx0 = ((xrow0 + rr0) << 10) + gchunk * 8;
  const size_t gx1 = ((xrow0 + rr1) << 10) + gchunk * 8;
  const int da0 = (w * 2 + 0) * 512 + lane * 8;
  const int da1 = (w * 2 + 1) * 512 + lane * 8;

  // A fragment bases: fb[k][mi] = (( (t*3+k)*64 + ut*8 + wu*2 + mi ) << 14)
  size_t fb[3][2];
#pragma unroll
  for (int k = 0; k < 3; ++k)
#pragma unroll
    for (int mi = 0; mi < 2; ++mi)
      fb[k][mi] = ((size_t)((t * 3 + k) * 64 + ut * 8 + wu * 2 + mi)) << 14;

  f32x4 pacc[3][2][4];
#pragma unroll
  for (int k = 0; k < 3; ++k)
#pragma unroll
    for (int i = 0; i < 2; ++i)
#pragma unroll
      for (int j = 0; j < 4; ++j) pacc[k][i][j] = f32x4{0.f, 0.f, 0.f, 0.f};

  short8 afr[3][2][2];
  uint4 p0, p1;

  // ---- prologue: B chunk 0 -> buf0 ----
  p0 = *(const uint4*)(xt + gx0);
  p1 = *(const uint4*)(xt + gx1);
  *(uint4*)&buf0[da0] = p0;
  *(uint4*)&buf0[da1] = p1;
  __syncthreads();

  // ---- main K loop: 16 chunks, unrolled x2 for static buffer pointers ----
#pragma unroll 1
  for (int it = 0; it < 8; ++it) {
    const int vc = it * 2;
    // even chunk: B in buf0
    LOAD_A(vc);
    p0 = *(const uint4*)(xt + gx0 + (size_t)(vc + 1) * 64);   // B vc+1
    p1 = *(const uint4*)(xt + gx1 + (size_t)(vc + 1) * 64);
    __builtin_amdgcn_s_setprio(1);
    BURST(buf0);
    __builtin_amdgcn_s_setprio(0);
    *(uint4*)&buf1[da0] = p0;
    *(uint4*)&buf1[da1] = p1;
    SOFT_BARRIER();
    // odd chunk: B in buf1
    LOAD_A(vc + 1);
    if (vc + 1 < 15) {
      p0 = *(const uint4*)(xt + gx0 + (size_t)(vc + 2) * 64); // B vc+2
      p1 = *(const uint4*)(xt + gx1 + (size_t)(vc + 2) * 64);
    }
    __builtin_amdgcn_s_setprio(1);
    BURST(buf1);
    __builtin_amdgcn_s_setprio(0);
    if (vc + 1 < 15) {
      *(uint4*)&buf0[da0] = p0;
      *(uint4*)&buf0[da1] = p1;
    }
    SOFT_BARRIER();
  }

  // ---- stage 2: oacc += P_k @ ThetaT[k], k fully unrolled ----
  f32x4 oacc[2][4];
#pragma unroll
  for (int i = 0; i < 2; ++i)
#pragma unroll
    for (int j = 0; j < 4; ++j) oacc[i][j] = f32x4{0.f, 0.f, 0.f, 0.f};

#pragma unroll
  for (int k = 0; k < 3; ++k) {
    __syncthreads();  // prev readers of sP/sTh done
#pragma unroll
    for (int mi = 0; mi < 2; ++mi)
#pragma unroll
      for (int ni = 0; ni < 4; ++ni)
#pragma unroll
        for (int r = 0; r < 4; ++r)
          sP[(mi * 16 + quad * 4 + r) * LDT + ni * 16 + l15] = f2bf(pacc[k][mi][ni][r]);
    for (int e = tid; e < 4096; e += 512) {
      const int f = e >> 6, o = e & 63;
      sTh[o * LDT + f] = f2bf(Theta[k * 4096 + e]);
    }
    __syncthreads();
#pragma unroll
    for (int ks = 0; ks < 2; ++ks) {
      short8 a2[2], b2[4];
#pragma unroll
      for (int mi = 0; mi < 2; ++mi)
        a2[mi] = *(const short8*)&sP[(mi * 16 + l15) * LDT + ks * 32 + quad * 8];
#pragma unroll
      for (int ni = 0; ni < 4; ++ni)
        b2[ni] = *(const short8*)&sTh[(ni * 16 + l15) * LDT + ks * 32 + quad * 8];
#pragma unroll
      for (int mi = 0; mi < 2; ++mi)
#pragma unroll
        for (int ni = 0; ni < 4; ++ni)
          oacc[mi][ni] = MFMA(a2[mi], b2[ni], oacc[mi][ni]);
    }
  }

  // ---- epilogue: relu + store ----
#pragma unroll
  for (int mi = 0; mi < 2; ++mi) {
    const int u_base = u0 + wu * 32 + mi * 16 + quad * 4;
#pragma unroll
    for (int ni = 0; ni < 4; ++ni) {
      const int n = n0 + wn * 64 + ni * 16 + l15;
      const int b = n >> 6, oo = n & 63;
      float* op = out + (((size_t)b * 12 + t) * 1000) * 64 + oo;
#pragma unroll
      for (int r = 0; r < 4; ++r) {
        const int u = u_base + r;
        if (u < 1000) op[(size_t)u * 64] = fmaxf(oacc[mi][ni][r], 0.f);
      }
    }
  }
}

// ---------------------------------------------------------------------------
extern "C" void kernel_launch(void* const* d_in, const int* in_sizes, int n_in,
                              void* d_out, int out_size, void* d_ws, size_t ws_size,
                              hipStream_t stream) {
  const float* x     = (const float*)d_in[0];
  const float* Att   = (const float*)d_in[1];
  const float* cheb  = (const float*)d_in[2];
  const float* Theta = (const float*)d_in[3];
  float* out = (float*)d_out;

  ushort* Mf  = (ushort*)d_ws;                 // 36*1024*1024 bf16, frag order
  ushort* xtw = Mf + 37748736ull;              // 12*2048*1024 bf16
  // requires ws_size >= 125,829,120 bytes

  build_m<<<147456, 256, 0, stream>>>(Att, cheb, Mf);
  transpose_x<<<dim3(16, 12, 32), 256, 0, stream>>>(x, xtw);
  cheb_main<<<1536, 512, 0, stream>>>(Mf, xtw, Theta, out);
}